// Round 1
// baseline (1567.721 us; speedup 1.0000x reference)
//
#include <hip/hip_runtime.h>

// BERTSyntaxRel: B=32 S=1024 D=768 H=128 R=48
//   gathered[b,t] = head_id==0 ? root : x[b, head_id-1]
//   head = relu(gathered@Wh+bh); tail = relu(x@Wt+bt)
//   out[b,s,r] = sum_h sum_k head[h] * kernel[h, r*128+k] * tail[k]
//
// f32 baseline (no fp32 MFMA on CDNA4 -> vector ALU).
// Kernel 1: fused head/tail FF GEMM (64 tok x 128 col tiles) -> ws
// Kernel 2: biaffine, 64-token tile, head/tail in LDS, kernel streamed from L2.

#define BB 32
#define SS 1024
#define DD 768
#define HH 128
#define RR 48
#define NTOK (BB * SS)

__global__ __launch_bounds__(256) void ff_kernel(
    const float* __restrict__ x, const int* __restrict__ head_id,
    const float* __restrict__ root,
    const float* __restrict__ Wh, const float* __restrict__ bh,
    const float* __restrict__ Wt, const float* __restrict__ bt,
    float* __restrict__ headm, float* __restrict__ tailm)
{
    const int tid = threadIdx.x;
    const int tile = blockIdx.x;
    const bool is_head = (blockIdx.y == 0);

    const float* __restrict__ W    = is_head ? Wh : Wt;
    const float* __restrict__ bias = is_head ? bh : bt;
    float* __restrict__ outm       = is_head ? headm : tailm;

    __shared__ float Als[32][68];    // [k][t], pad 4: transposed A tile
    __shared__ float Wls[32][128];   // [k][c]

    // loader assignment: row lt, two float4s per k-chunk
    const int lt = tid >> 2;                 // 0..63
    const int tok_l = tile * 64 + lt;
    const float* srcrow;
    if (is_head) {
        const int hid = head_id[tok_l];
        const int b = tok_l >> 10;           // tok / S
        srcrow = (hid == 0) ? root : (x + ((size_t)(b * SS + hid - 1)) * DD);
    } else {
        srcrow = x + (size_t)tok_l * DD;
    }

    const int tg = tid & 15;                 // token group: tokens tg*4 .. tg*4+3
    const int cg = tid >> 4;                 // col group:   cols  cg*8 .. cg*8+7
    const int c0 = cg * 8;

    float acc[4][8];
    #pragma unroll
    for (int i = 0; i < 4; ++i)
        #pragma unroll
        for (int j = 0; j < 8; ++j) acc[i][j] = 0.f;

    for (int kb = 0; kb < DD; kb += 32) {
        // stage A transposed: [k][t]
        #pragma unroll
        for (int it = 0; it < 2; ++it) {
            const int k = (tid & 3) * 4 + it * 16;
            const float4 v = *(const float4*)(srcrow + kb + k);
            Als[k + 0][lt] = v.x; Als[k + 1][lt] = v.y;
            Als[k + 2][lt] = v.z; Als[k + 3][lt] = v.w;
        }
        // stage W: 32 rows x 128 cols = 1024 float4, 4 per thread
        #pragma unroll
        for (int it = 0; it < 4; ++it) {
            const int fi = tid + it * 256;
            const int kr = fi >> 5;              // 32 float4 per row
            const int cc = (fi & 31) * 4;
            *(float4*)&Wls[kr][cc] = *(const float4*)(W + (size_t)(kb + kr) * HH + cc);
        }
        __syncthreads();

        #pragma unroll
        for (int kc = 0; kc < 32; ++kc) {
            const float4 a  = *(const float4*)&Als[kc][tg * 4];
            const float4 w0 = *(const float4*)&Wls[kc][c0];
            const float4 w1 = *(const float4*)&Wls[kc][c0 + 4];
            const float av[4] = {a.x, a.y, a.z, a.w};
            const float wv[8] = {w0.x, w0.y, w0.z, w0.w, w1.x, w1.y, w1.z, w1.w};
            #pragma unroll
            for (int i = 0; i < 4; ++i)
                #pragma unroll
                for (int j = 0; j < 8; ++j)
                    acc[i][j] = fmaf(av[i], wv[j], acc[i][j]);
        }
        __syncthreads();
    }

    float bv[8];
    #pragma unroll
    for (int j = 0; j < 8; ++j) bv[j] = bias[c0 + j];

    #pragma unroll
    for (int i = 0; i < 4; ++i) {
        const int tok = tile * 64 + tg * 4 + i;
        float4 o0, o1;
        o0.x = fmaxf(acc[i][0] + bv[0], 0.f);
        o0.y = fmaxf(acc[i][1] + bv[1], 0.f);
        o0.z = fmaxf(acc[i][2] + bv[2], 0.f);
        o0.w = fmaxf(acc[i][3] + bv[3], 0.f);
        o1.x = fmaxf(acc[i][4] + bv[4], 0.f);
        o1.y = fmaxf(acc[i][5] + bv[5], 0.f);
        o1.z = fmaxf(acc[i][6] + bv[6], 0.f);
        o1.w = fmaxf(acc[i][7] + bv[7], 0.f);
        *(float4*)(outm + (size_t)tok * HH + c0)     = o0;
        *(float4*)(outm + (size_t)tok * HH + c0 + 4) = o1;
    }
}

// biaffine: out[t,r] = sum_h head[t,h] * (sum_k kernel[h, r*128+k] * tail[t,k])
// thread: 4 tokens (tg+16i) x 3 r (rg, rg+16, rg+32); 16-lane broadcast groups
// make kernel[] reads wave-uniform per rg -> coalescer merges.
__global__ __launch_bounds__(256) void biaffine_kernel(
    const float* __restrict__ headm, const float* __restrict__ tailm,
    const float* __restrict__ kern, float* __restrict__ out)
{
    __shared__ float Hls[64][HH + 4];
    __shared__ float Tls[64][HH + 4];
    const int tid = threadIdx.x;
    const int tile = blockIdx.x;

    #pragma unroll
    for (int it = 0; it < 8; ++it) {
        const int fi = tid + it * 256;           // 0..2047
        const int t = fi >> 5;                   // 32 float4 per row
        const int cc = (fi & 31) * 4;
        *(float4*)&Hls[t][cc] =
            *(const float4*)(headm + ((size_t)(tile * 64 + t)) * HH + cc);
        *(float4*)&Tls[t][cc] =
            *(const float4*)(tailm + ((size_t)(tile * 64 + t)) * HH + cc);
    }
    __syncthreads();

    const int tg = tid & 15;
    const int rg = tid >> 4;

    float acc[4][3];
    #pragma unroll
    for (int i = 0; i < 4; ++i)
        #pragma unroll
        for (int j = 0; j < 3; ++j) acc[i][j] = 0.f;

    for (int h = 0; h < HH; ++h) {
        float hreg[4];
        #pragma unroll
        for (int i = 0; i < 4; ++i) hreg[i] = Hls[tg + 16 * i][h];

        const float* kp  = kern + (size_t)h * (RR * HH);
        const float* kp0 = kp + (size_t)rg * HH;
        const float* kp1 = kp + (size_t)(rg + 16) * HH;
        const float* kp2 = kp + (size_t)(rg + 32) * HH;

        #pragma unroll 8
        for (int k = 0; k < HH; k += 4) {
            const float4 k0 = *(const float4*)(kp0 + k);
            const float4 k1 = *(const float4*)(kp1 + k);
            const float4 k2 = *(const float4*)(kp2 + k);
            #pragma unroll
            for (int i = 0; i < 4; ++i) {
                const float4 tv = *(const float4*)&Tls[tg + 16 * i][k];
                const float p0 = hreg[i] * tv.x;
                const float p1 = hreg[i] * tv.y;
                const float p2 = hreg[i] * tv.z;
                const float p3 = hreg[i] * tv.w;
                acc[i][0] = fmaf(p0, k0.x, fmaf(p1, k0.y, fmaf(p2, k0.z, fmaf(p3, k0.w, acc[i][0]))));
                acc[i][1] = fmaf(p0, k1.x, fmaf(p1, k1.y, fmaf(p2, k1.z, fmaf(p3, k1.w, acc[i][1]))));
                acc[i][2] = fmaf(p0, k2.x, fmaf(p1, k2.y, fmaf(p2, k2.z, fmaf(p3, k2.w, acc[i][2]))));
            }
        }
    }

    #pragma unroll
    for (int i = 0; i < 4; ++i) {
        const int tok = tile * 64 + tg + 16 * i;
        out[(size_t)tok * RR + rg]      = acc[i][0];
        out[(size_t)tok * RR + rg + 16] = acc[i][1];
        out[(size_t)tok * RR + rg + 32] = acc[i][2];
    }
}

extern "C" void kernel_launch(void* const* d_in, const int* in_sizes, int n_in,
                              void* d_out, int out_size, void* d_ws, size_t ws_size,
                              hipStream_t stream)
{
    const float* x    = (const float*)d_in[0];
    const int*   hid  = (const int*)d_in[1];
    const float* root = (const float*)d_in[2];
    const float* Wh   = (const float*)d_in[3];
    const float* bh   = (const float*)d_in[4];
    const float* Wt   = (const float*)d_in[5];
    const float* bt   = (const float*)d_in[6];
    const float* kern = (const float*)d_in[7];
    float* out = (float*)d_out;

    // ws: head (16.8 MB) + tail (16.8 MB), fully overwritten every launch
    float* headm = (float*)d_ws;
    float* tailm = headm + (size_t)NTOK * HH;

    dim3 ffgrid(NTOK / 64, 2);
    ff_kernel<<<ffgrid, 256, 0, stream>>>(x, hid, root, Wh, bh, Wt, bt, headm, tailm);
    biaffine_kernel<<<NTOK / 64, 256, 0, stream>>>(headm, tailm, kern, out);
}

// Round 5
// 339.279 us; speedup vs baseline: 4.6207x; 4.6207x over previous
//
#include <hip/hip_runtime.h>

// BERTSyntaxRel: B=32 S=1024 D=768 H=128 R=48
// out[t,r] = sum_{h,k} head[t,h] * kern[h, r*128+k] * tail[t,k]
//          = (Z @ K2)[t, r]   with Z[t, hk] = head[t,h]*tail[t,k]  (rank-1 rows)
// Kernel 1 (prep): shuffle kern -> f16 MFMA B-fragments (coalesced layout)
// Kernel 2 (ff):   f32 VALU FF (gather+relu GEMM), outputs f16 head/tail
// Kernel 3 (biaffine_mfma): Z@K2 via mfma_f32_16x16x32_f16, A-frags built
//          in-register (v_pk_mul_f16), k-split across waves + LDS reduce.

#define BB 32
#define SS 1024
#define DD 768
#define HH 128
#define RR 48
#define NTOK (BB * SS)

typedef _Float16 f16;
typedef _Float16 f16x8 __attribute__((ext_vector_type(8)));
typedef float f32x4 __attribute__((ext_vector_type(4)));

// ---------------- prep: pack kernel (f32 128x6144) into f16 B-frags ----------
// Bp[(((h*4+kw)*3+n)*64+l)*8+j] = kern[h][(n*16+(l&15))*128 + kw*32 + (l>>4)*8 + j]
__global__ __launch_bounds__(256) void prep_kernel(
    const float* __restrict__ kern, f16* __restrict__ Bp)
{
    const int idx = blockIdx.x * 256 + threadIdx.x;   // < 786432
    const int j = idx & 7;
    const int l = (idx >> 3) & 63;
    int rem = idx >> 9;
    const int n = rem % 3;
    rem /= 3;
    const int kw = rem & 3;
    const int h = rem >> 2;
    const int r = n * 16 + (l & 15);
    const int k = kw * 32 + (l >> 4) * 8 + j;
    Bp[idx] = (f16)kern[(size_t)h * (RR * HH) + (size_t)r * HH + k];
}

// ---------------- FF: f32 compute, f16 output ----------------
__global__ __launch_bounds__(256) void ff_kernel(
    const float* __restrict__ x, const int* __restrict__ head_id,
    const float* __restrict__ root,
    const float* __restrict__ Wh, const float* __restrict__ bh,
    const float* __restrict__ Wt, const float* __restrict__ bt,
    f16* __restrict__ headm, f16* __restrict__ tailm)
{
    const int tid = threadIdx.x;
    const int tile = blockIdx.x;
    const bool is_head = (blockIdx.y == 0);

    const float* __restrict__ W    = is_head ? Wh : Wt;
    const float* __restrict__ bias = is_head ? bh : bt;
    f16* __restrict__ outm         = is_head ? headm : tailm;

    __shared__ float Als[32][68];
    __shared__ float Wls[32][128];

    const int lt = tid >> 2;
    const int tok_l = tile * 64 + lt;
    const float* srcrow;
    if (is_head) {
        const int hid = head_id[tok_l];
        const int b = tok_l >> 10;
        srcrow = (hid == 0) ? root : (x + ((size_t)(b * SS + hid - 1)) * DD);
    } else {
        srcrow = x + (size_t)tok_l * DD;
    }

    const int tg = tid & 15;
    const int cg = tid >> 4;
    const int c0 = cg * 8;

    float acc[4][8];
    #pragma unroll
    for (int i = 0; i < 4; ++i)
        #pragma unroll
        for (int j = 0; j < 8; ++j) acc[i][j] = 0.f;

    for (int kb = 0; kb < DD; kb += 32) {
        #pragma unroll
        for (int it = 0; it < 2; ++it) {
            const int k = (tid & 3) * 4 + it * 16;
            const float4 v = *(const float4*)(srcrow + kb + k);
            Als[k + 0][lt] = v.x; Als[k + 1][lt] = v.y;
            Als[k + 2][lt] = v.z; Als[k + 3][lt] = v.w;
        }
        #pragma unroll
        for (int it = 0; it < 4; ++it) {
            const int fi = tid + it * 256;
            const int kr = fi >> 5;
            const int cc = (fi & 31) * 4;
            *(float4*)&Wls[kr][cc] = *(const float4*)(W + (size_t)(kb + kr) * HH + cc);
        }
        __syncthreads();

        #pragma unroll
        for (int kc = 0; kc < 32; ++kc) {
            const float4 a  = *(const float4*)&Als[kc][tg * 4];
            const float4 w0 = *(const float4*)&Wls[kc][c0];
            const float4 w1 = *(const float4*)&Wls[kc][c0 + 4];
            const float av[4] = {a.x, a.y, a.z, a.w};
            const float wv[8] = {w0.x, w0.y, w0.z, w0.w, w1.x, w1.y, w1.z, w1.w};
            #pragma unroll
            for (int i = 0; i < 4; ++i)
                #pragma unroll
                for (int j = 0; j < 8; ++j)
                    acc[i][j] = fmaf(av[i], wv[j], acc[i][j]);
        }
        __syncthreads();
    }

    float bv[8];
    #pragma unroll
    for (int j = 0; j < 8; ++j) bv[j] = bias[c0 + j];

    #pragma unroll
    for (int i = 0; i < 4; ++i) {
        const int tok = tile * 64 + tg * 4 + i;
        f16x8 ov;
        #pragma unroll
        for (int j = 0; j < 8; ++j)
            ov[j] = (f16)fmaxf(acc[i][j] + bv[j], 0.f);
        *(f16x8*)(outm + (size_t)tok * HH + c0) = ov;
    }
}

// ---------------- biaffine via MFMA ----------------
// block = 512 thr (8 waves) = 128 tokens; wave (g = tile-group of 4, q = h-quarter)
// per wave: 4 token-tiles x 32 h x 4 kw x 3 n-tiles -> 1536 MFMA
__global__ __launch_bounds__(512, 2) void biaffine_mfma(
    const f16* __restrict__ headm, const f16* __restrict__ tailm,
    const f16* __restrict__ Bp, float* __restrict__ out)
{
    __shared__ float red[6 * 12 * 4 * 64];   // 73.7 KB: [(q-1)*2+g][i*3+n][word][lane]

    const int tid  = threadIdx.x;
    const int lane = tid & 63;
    const int wv   = tid >> 6;
    const int g    = wv & 1;      // tile-group
    const int q    = wv >> 1;     // h-quarter
    const int lr   = lane & 15;
    const int lg   = lane >> 4;
    const int tok0 = blockIdx.x * 128 + g * 64;

    // per-lane head/tail rows (token = tok0 + i*16 + lr)
    f16x8 hrv[4][4];   // [tile][c]: h = q*32 + c*8 + e
    f16x8 trg[4][4];   // [tile][kw]: k = kw*32 + lg*8 + j
    #pragma unroll
    for (int i = 0; i < 4; ++i) {
        const f16* hp = headm + (size_t)(tok0 + i * 16 + lr) * HH + q * 32;
        const f16* tp = tailm + (size_t)(tok0 + i * 16 + lr) * HH + lg * 8;
        #pragma unroll
        for (int c = 0; c < 4; ++c)  hrv[i][c]  = *(const f16x8*)(hp + c * 8);
        #pragma unroll
        for (int kw = 0; kw < 4; ++kw) trg[i][kw] = *(const f16x8*)(tp + kw * 32);
    }

    f32x4 acc[4][3];
    #pragma unroll
    for (int i = 0; i < 4; ++i)
        #pragma unroll
        for (int n = 0; n < 3; ++n) acc[i][n] = (f32x4)0.f;

    const f16* bq = Bp + (size_t)(q * 32) * 6144;   // per-h B block = 4*3*512 f16

    #pragma unroll
    for (int h = 0; h < 32; ++h) {
        f16 hs[4];
        #pragma unroll
        for (int i = 0; i < 4; ++i) hs[i] = hrv[i][h >> 3][h & 7];

        #pragma unroll
        for (int kw = 0; kw < 4; ++kw) {
            const f16* bp = bq + ((size_t)(h * 4 + kw) * 3) * 512 + lane * 8;
            f16x8 bf0 = *(const f16x8*)(bp);
            f16x8 bf1 = *(const f16x8*)(bp + 512);
            f16x8 bf2 = *(const f16x8*)(bp + 1024);
            #pragma unroll
            for (int i = 0; i < 4; ++i) {
                const f16x8 af = hs[i] * trg[i][kw];   // v_pk_mul_f16 x4
                acc[i][0] = __builtin_amdgcn_mfma_f32_16x16x32_f16(af, bf0, acc[i][0], 0, 0, 0);
                acc[i][1] = __builtin_amdgcn_mfma_f32_16x16x32_f16(af, bf1, acc[i][1], 0, 0, 0);
                acc[i][2] = __builtin_amdgcn_mfma_f32_16x16x32_f16(af, bf2, acc[i][2], 0, 0, 0);
            }
        }
    }

    // cross-wave k-reduction (h-quarters) via LDS, word-plane layout (conflict-free)
    if (q > 0) {
        const int reg = (q - 1) * 2 + g;
        #pragma unroll
        for (int i = 0; i < 4; ++i)
            #pragma unroll
            for (int n = 0; n < 3; ++n)
                #pragma unroll
                for (int w = 0; w < 4; ++w)
                    red[((reg * 12 + i * 3 + n) * 4 + w) * 64 + lane] = acc[i][n][w];
    }
    __syncthreads();
    if (q == 0) {
        #pragma unroll
        for (int qq = 1; qq < 4; ++qq) {
            const int reg = (qq - 1) * 2 + g;
            #pragma unroll
            for (int i = 0; i < 4; ++i)
                #pragma unroll
                for (int n = 0; n < 3; ++n)
                    #pragma unroll
                    for (int w = 0; w < 4; ++w)
                        acc[i][n][w] += red[((reg * 12 + i * 3 + n) * 4 + w) * 64 + lane];
        }
        // C layout: col = lane&15 (-> r = n*16+lr), row = (lane>>4)*4 + w (-> token)
        #pragma unroll
        for (int i = 0; i < 4; ++i)
            #pragma unroll
            for (int n = 0; n < 3; ++n)
                #pragma unroll
                for (int w = 0; w < 4; ++w)
                    out[(size_t)(tok0 + i * 16 + lg * 4 + w) * RR + n * 16 + lr] = acc[i][n][w];
    }
}

extern "C" void kernel_launch(void* const* d_in, const int* in_sizes, int n_in,
                              void* d_out, int out_size, void* d_ws, size_t ws_size,
                              hipStream_t stream)
{
    const float* x    = (const float*)d_in[0];
    const int*   hid  = (const int*)d_in[1];
    const float* root = (const float*)d_in[2];
    const float* Wh   = (const float*)d_in[3];
    const float* bh   = (const float*)d_in[4];
    const float* Wt   = (const float*)d_in[5];
    const float* bt   = (const float*)d_in[6];
    const float* kern = (const float*)d_in[7];
    float* out = (float*)d_out;

    // ws: headm f16 (8.39 MB) + tailm f16 (8.39 MB) + Bp f16 (1.57 MB)
    f16* headm = (f16*)d_ws;
    f16* tailm = headm + (size_t)NTOK * HH;
    f16* Bp    = tailm + (size_t)NTOK * HH;

    prep_kernel<<<(HH * RR * HH) / 256, 256, 0, stream>>>(kern, Bp);
    dim3 ffgrid(NTOK / 64, 2);
    ff_kernel<<<ffgrid, 256, 0, stream>>>(x, hid, root, Wh, bh, Wt, bt, headm, tailm);
    biaffine_mfma<<<NTOK / 128, 512, 0, stream>>>(headm, tailm, Bp, out);
}

// Round 9
// 266.016 us; speedup vs baseline: 5.8933x; 1.2754x over previous
//
#include <hip/hip_runtime.h>

// BERTSyntaxRel: B=32 S=1024 D=768 H=128 R=48
// out[t,r] = sum_{h,k} head[t,h] * kern[h, r*128+k] * tail[t,k]
//          = (Z @ K2)[t, r]   with Z[t, hk] = head[t,h]*tail[t,k]  (rank-1 rows)
// prep_kernel: kern -> f16 MFMA B-frags (Bp)
// prep_w:      Wh/Wt -> f16 MFMA B-frags (Whp/Wtp)
// ff_mfma:     head/tail FF via mfma_f32_16x16x32_f16, LDS-free, gather fused
// biaffine_mfma: Z@K2 via MFMA, A-frags in-register, k-split + LDS reduce

#define BB 32
#define SS 1024
#define DD 768
#define HH 128
#define RR 48
#define NTOK (BB * SS)

typedef _Float16 f16;
typedef _Float16 f16x8 __attribute__((ext_vector_type(8)));
typedef float f32x4 __attribute__((ext_vector_type(4)));

// ---------------- prep: pack kernel (f32 128x6144) into f16 B-frags ----------
// Bp[(((h*4+kw)*3+n)*64+l)*8+j] = kern[h][(n*16+(l&15))*128 + kw*32 + (l>>4)*8 + j]
__global__ __launch_bounds__(256) void prep_kernel(
    const float* __restrict__ kern, f16* __restrict__ Bp)
{
    const int idx = blockIdx.x * 256 + threadIdx.x;   // < 786432
    const int j = idx & 7;
    const int l = (idx >> 3) & 63;
    int rem = idx >> 9;
    const int n = rem % 3;
    rem /= 3;
    const int kw = rem & 3;
    const int h = rem >> 2;
    const int r = n * 16 + (l & 15);
    const int k = kw * 32 + (l >> 4) * 8 + j;
    Bp[idx] = (f16)kern[(size_t)h * (RR * HH) + (size_t)r * HH + k];
}

// ---------------- prep_w: pack W (f32 768x128) into f16 B-frags ----------
// Wp[((s*8+n)*64+l)*8+j] = W[(s*32+(l>>4)*8+j)*128 + n*16+(l&15)]
__global__ __launch_bounds__(256) void prep_w(
    const float* __restrict__ Wh, const float* __restrict__ Wt,
    f16* __restrict__ Whp, f16* __restrict__ Wtp)
{
    const int idx = blockIdx.x * 256 + threadIdx.x;   // < 98304
    const float* __restrict__ W = blockIdx.y ? Wt : Wh;
    f16* __restrict__ Wp        = blockIdx.y ? Wtp : Whp;
    const int j = idx & 7;
    const int l = (idx >> 3) & 63;
    const int rem = idx >> 9;
    const int n = rem & 7;
    const int s = rem >> 3;
    const int k = s * 32 + (l >> 4) * 8 + j;
    const int c = n * 16 + (l & 15);
    Wp[idx] = (f16)W[(size_t)k * HH + c];
}

// ---------------- FF via MFMA: M=NTOK N=128 K=768, LDS-free ----------------
// block = 256 thr (4 waves) = 64 tokens; wave = 16-token tile, all 8 n-tiles.
// A-frag: lane l -> row tok0+(l&15), k=(l>>4)*8+j (f32 load + cvt).
// grid.y: 0 = head branch (gather), 1 = tail branch.
__global__ __launch_bounds__(256) void ff_mfma(
    const float* __restrict__ x, const int* __restrict__ head_id,
    const float* __restrict__ root,
    const f16* __restrict__ Whp, const float* __restrict__ bh,
    const f16* __restrict__ Wtp, const float* __restrict__ bt,
    f16* __restrict__ headm, f16* __restrict__ tailm)
{
    const int tid  = threadIdx.x;
    const int lane = tid & 63;
    const int w    = tid >> 6;
    const bool is_head = (blockIdx.y == 0);

    const f16*   __restrict__ Wp   = is_head ? Whp : Wtp;
    const float* __restrict__ bias = is_head ? bh : bt;
    f16*         __restrict__ outm = is_head ? headm : tailm;

    const int lr = lane & 15;
    const int lg = lane >> 4;
    const int tok0 = blockIdx.x * 64 + w * 16;
    const int tk = tok0 + lr;

    const float* srcrow;
    if (is_head) {
        const int hid = head_id[tk];
        const int b = tk >> 10;
        srcrow = (hid == 0) ? root : (x + ((size_t)(b * SS + hid - 1)) * DD);
    } else {
        srcrow = x + (size_t)tk * DD;
    }
    srcrow += lg * 8;

    f32x4 acc[8];
    #pragma unroll
    for (int n = 0; n < 8; ++n) acc[n] = (f32x4)0.f;

    for (int s = 0; s < DD / 32; ++s) {        // 24 K-steps
        const float4 a0 = *(const float4*)(srcrow + s * 32);
        const float4 a1 = *(const float4*)(srcrow + s * 32 + 4);
        f16x8 af;
        af[0] = (f16)a0.x; af[1] = (f16)a0.y; af[2] = (f16)a0.z; af[3] = (f16)a0.w;
        af[4] = (f16)a1.x; af[5] = (f16)a1.y; af[6] = (f16)a1.z; af[7] = (f16)a1.w;

        const f16* bp = Wp + (size_t)(s * 8) * 512 + lane * 8;
        #pragma unroll
        for (int n = 0; n < 8; ++n) {
            const f16x8 bf = *(const f16x8*)(bp + n * 512);
            acc[n] = __builtin_amdgcn_mfma_f32_16x16x32_f16(af, bf, acc[n], 0, 0, 0);
        }
    }

    float bv[8];
    #pragma unroll
    for (int n = 0; n < 8; ++n) bv[n] = bias[n * 16 + lr];

    // C layout: col = lane&15 (-> h = n*16+lr), row = (lane>>4)*4 + wi (-> token)
    #pragma unroll
    for (int wi = 0; wi < 4; ++wi) {
        const int tr = tok0 + lg * 4 + wi;
        #pragma unroll
        for (int n = 0; n < 8; ++n)
            outm[(size_t)tr * HH + n * 16 + lr] = (f16)fmaxf(acc[n][wi] + bv[n], 0.f);
    }
}

// ---------------- biaffine via MFMA ----------------
// block = 512 thr (8 waves) = 128 tokens; wave (g = tile-group of 4, q = h-quarter)
__global__ __launch_bounds__(512, 2) void biaffine_mfma(
    const f16* __restrict__ headm, const f16* __restrict__ tailm,
    const f16* __restrict__ Bp, float* __restrict__ out)
{
    __shared__ float red[6 * 12 * 4 * 64];   // 73.7 KB

    const int tid  = threadIdx.x;
    const int lane = tid & 63;
    const int wv   = tid >> 6;
    const int g    = wv & 1;      // tile-group
    const int q    = wv >> 1;     // h-quarter
    const int lr   = lane & 15;
    const int lg   = lane >> 4;
    const int tok0 = blockIdx.x * 128 + g * 64;

    f16x8 hrv[4][4];   // [tile][c]: h = q*32 + c*8 + e
    f16x8 trg[4][4];   // [tile][kw]: k = kw*32 + lg*8 + j
    #pragma unroll
    for (int i = 0; i < 4; ++i) {
        const f16* hp = headm + (size_t)(tok0 + i * 16 + lr) * HH + q * 32;
        const f16* tp = tailm + (size_t)(tok0 + i * 16 + lr) * HH + lg * 8;
        #pragma unroll
        for (int c = 0; c < 4; ++c)  hrv[i][c]  = *(const f16x8*)(hp + c * 8);
        #pragma unroll
        for (int kw = 0; kw < 4; ++kw) trg[i][kw] = *(const f16x8*)(tp + kw * 32);
    }

    f32x4 acc[4][3];
    #pragma unroll
    for (int i = 0; i < 4; ++i)
        #pragma unroll
        for (int n = 0; n < 3; ++n) acc[i][n] = (f32x4)0.f;

    const f16* bq = Bp + (size_t)(q * 32) * 6144;

    #pragma unroll
    for (int h = 0; h < 32; ++h) {
        f16 hs[4];
        #pragma unroll
        for (int i = 0; i < 4; ++i) hs[i] = hrv[i][h >> 3][h & 7];

        #pragma unroll
        for (int kw = 0; kw < 4; ++kw) {
            const f16* bp = bq + ((size_t)(h * 4 + kw) * 3) * 512 + lane * 8;
            f16x8 bf0 = *(const f16x8*)(bp);
            f16x8 bf1 = *(const f16x8*)(bp + 512);
            f16x8 bf2 = *(const f16x8*)(bp + 1024);
            #pragma unroll
            for (int i = 0; i < 4; ++i) {
                const f16x8 af = hs[i] * trg[i][kw];   // v_pk_mul_f16 x4
                acc[i][0] = __builtin_amdgcn_mfma_f32_16x16x32_f16(af, bf0, acc[i][0], 0, 0, 0);
                acc[i][1] = __builtin_amdgcn_mfma_f32_16x16x32_f16(af, bf1, acc[i][1], 0, 0, 0);
                acc[i][2] = __builtin_amdgcn_mfma_f32_16x16x32_f16(af, bf2, acc[i][2], 0, 0, 0);
            }
        }
    }

    if (q > 0) {
        const int reg = (q - 1) * 2 + g;
        #pragma unroll
        for (int i = 0; i < 4; ++i)
            #pragma unroll
            for (int n = 0; n < 3; ++n)
                #pragma unroll
                for (int w = 0; w < 4; ++w)
                    red[((reg * 12 + i * 3 + n) * 4 + w) * 64 + lane] = acc[i][n][w];
    }
    __syncthreads();
    if (q == 0) {
        #pragma unroll
        for (int qq = 1; qq < 4; ++qq) {
            const int reg = (qq - 1) * 2 + g;
            #pragma unroll
            for (int i = 0; i < 4; ++i)
                #pragma unroll
                for (int n = 0; n < 3; ++n)
                    #pragma unroll
                    for (int w = 0; w < 4; ++w)
                        acc[i][n][w] += red[((reg * 12 + i * 3 + n) * 4 + w) * 64 + lane];
        }
        #pragma unroll
        for (int i = 0; i < 4; ++i)
            #pragma unroll
            for (int n = 0; n < 3; ++n)
                #pragma unroll
                for (int w = 0; w < 4; ++w)
                    out[(size_t)(tok0 + i * 16 + lg * 4 + w) * RR + n * 16 + lr] = acc[i][n][w];
    }
}

extern "C" void kernel_launch(void* const* d_in, const int* in_sizes, int n_in,
                              void* d_out, int out_size, void* d_ws, size_t ws_size,
                              hipStream_t stream)
{
    const float* x    = (const float*)d_in[0];
    const int*   hid  = (const int*)d_in[1];
    const float* root = (const float*)d_in[2];
    const float* Wh   = (const float*)d_in[3];
    const float* bh   = (const float*)d_in[4];
    const float* Wt   = (const float*)d_in[5];
    const float* bt   = (const float*)d_in[6];
    const float* kern = (const float*)d_in[7];
    float* out = (float*)d_out;

    // ws: headm (8.39 MB) + tailm (8.39 MB) + Bp (1.57 MB) + Whp/Wtp (196 KB each)
    f16* headm = (f16*)d_ws;
    f16* tailm = headm + (size_t)NTOK * HH;
    f16* Bp    = tailm + (size_t)NTOK * HH;
    f16* Whp   = Bp + (size_t)HH * RR * HH;
    f16* Wtp   = Whp + (size_t)(DD / 32) * 8 * 512;

    prep_kernel<<<(HH * RR * HH) / 256, 256, 0, stream>>>(kern, Bp);
    dim3 wgrid((DD / 32) * 8 * 512 / 256, 2);
    prep_w<<<wgrid, 256, 0, stream>>>(Wh, Wt, Whp, Wtp);
    dim3 ffgrid(NTOK / 64, 2);
    ff_mfma<<<ffgrid, 256, 0, stream>>>(x, hid, root, Whp, bh, Wtp, bt, headm, tailm);
    biaffine_mfma<<<NTOK / 128, 512, 0, stream>>>(headm, tailm, Bp, out);
}